// Round 10
// baseline (16.934 us; speedup 1.0000x reference)
//
#include <hip/hip_runtime.h>

// Problem constants
constexpr int Bv   = 4;
constexpr int Lv   = 4096;
constexpr int Dv   = 128;
constexpr int Av   = 16;
constexpr int Wwin = 2*Av + 1;  // 33
constexpr int OUTv = 2;
constexpr int HIDv = 24;
constexpr int NROWS = Bv * Lv;  // 16384

constexpr int TILE  = 64;           // output rows per block
constexpr int SROWS = TILE + 2*Av;  // 96 staged rows
constexpr int NBLK  = NROWS / TILE; // 256
constexpr int NT    = 512;          // threads per block (8 waves)

typedef __attribute__((ext_vector_type(8))) short short8;   // 8 bf16 (4 VGPR)
typedef __attribute__((ext_vector_type(4))) short short4v;  // 4 bf16 (8B)
typedef __attribute__((ext_vector_type(4))) float f32x4;    // MFMA acc

__device__ __forceinline__ short f2bf(float f) {  // RNE fp32->bf16 (3 VALU)
    unsigned u = __builtin_bit_cast(unsigned, f);
    u += 0x7FFFu + ((u >> 16) & 1u);
    return (short)(u >> 16);
}

// ---------------------------------------------------------------------------
// Single fused kernel, TILE=64 rows/block (+16 halo each side), 8 waves.
//   W1 B-frags prefetched to regs pre-B1 (overlap with x staging)
//   Wf = Wv@fc2 per-block via MFMA (1 row-frag/wave)
//   h1 = relu(x@W1+b1) via MFMA (16 cols/wave, pure LDS+MFMA post-B1)
//   m  = h1@Wf via MFMA (2 frag-pairs/wave, waves 0-5)
//   33-tap window sum + fc2_b + relu; fc3 -> out; a-output = 1.0
// grid 256, 512 threads, LDS ~77.4 KB
__global__ __launch_bounds__(NT) void k_all(const float* __restrict__ x,
                                            const float* __restrict__ W1,
                                            const float* __restrict__ b1,
                                            const float* __restrict__ Wv,
                                            const float* __restrict__ fc2,
                                            const float* __restrict__ fc2b,
                                            const float* __restrict__ fc3w,
                                            const float* __restrict__ fc3b,
                                            float* __restrict__ out,
                                            float* __restrict__ aout) {
    __shared__ short sA[SROWS][136];    // x tile, bf16   (26112 B)
    __shared__ short sH[SROWS][136];    // h1, bf16       (26112 B)
    __shared__ short sWfT[32][136];     // Wf^T bf16      (8704 B)
    __shared__ float smv[SROWS][25];    // m, f32         (9600 B)
    __shared__ float sh2[TILE][25];     // h2, f32        (6400 B)
    __shared__ float sb1[Dv];           // 512 B

    const int t = threadIdx.x, blk = blockIdx.x;
    const int g0 = blk * TILE;               // global output row base
    const int bb = g0 >> 12;                 // batch index
    const int l0 = g0 & (Lv - 1);            // in-batch row base
    const int lane = t & 63, w = t >> 6;     // 8 waves
    const int arow = lane & 15;
    const int kgrp = (lane >> 4) * 8;
    const int crow = (lane >> 4) * 4;
    const int ncol0 = w * 16;                // GEMM1: 16 cols per wave

    // ---- phase 1: stage x tile (rows l0-16 .. l0+79), bf16, zero outside [0,Lv)
    for (int i = t; i < SROWS*32; i += NT) {           // 6 iters
        const int r = i >> 5, c4 = i & 31;
        const int l = l0 - Av + r;
        short4v o = {0, 0, 0, 0};
        if (l >= 0 && l < Lv) {
            const float4 v = *(const float4*)&x[((size_t)bb*Lv + l)*Dv + c4*4];
            o[0] = f2bf(v.x); o[1] = f2bf(v.y); o[2] = f2bf(v.z); o[3] = f2bf(v.w);
        }
        *(short4v*)&sA[r][c4*4] = o;
    }
    if (t < Dv) sb1[t] = b1[t];

    // ---- prefetch GEMM1 B-frags (16 cols/wave) from fp32 W1 into registers;
    //      loads overlap x-staging + Wf loads; post-B1 GEMM1 is pure LDS+MFMA
    short8 pb[4];
    {
        const int n0 = ncol0 + arow;
#pragma unroll
        for (int kb = 0; kb < 4; ++kb) {
            const int kof = kb*32 + kgrp;
            float a0[8];
#pragma unroll
            for (int j = 0; j < 8; ++j)
                a0[j] = W1[(size_t)(kof + j)*Dv + n0];
            short8 b0;
#pragma unroll
            for (int j = 0; j < 8; ++j) b0[j] = f2bf(a0[j]);
            pb[kb] = b0;
        }
    }

    // ---- phase 2: Wf = Wv @ fc2 via MFMA; wave w owns Wf rows [w*16, w*16+16)
    {
        f32x4 accW[2];
        accW[0] = (f32x4){0,0,0,0};
        accW[1] = (f32x4){0,0,0,0};
#pragma unroll
        for (int kb = 0; kb < 4; ++kb) {
            const int kof = kb*32 + kgrp;
            const int m = w*16 + arow;
            const float4 v0 = *(const float4*)&Wv[(size_t)m*Dv + kof];
            const float4 v1 = *(const float4*)&Wv[(size_t)m*Dv + kof + 4];
            short8 aW;
            aW[0] = f2bf(v0.x); aW[1] = f2bf(v0.y); aW[2] = f2bf(v0.z); aW[3] = f2bf(v0.w);
            aW[4] = f2bf(v1.x); aW[5] = f2bf(v1.y); aW[6] = f2bf(v1.z); aW[7] = f2bf(v1.w);
#pragma unroll
            for (int nf = 0; nf < 2; ++nf) {
                const int n = nf*16 + arow;
                short8 bW;
#pragma unroll
                for (int j = 0; j < 8; ++j) {
                    const float v = (n < HIDv) ? fc2[(size_t)(kof + j)*HIDv + n] : 0.f;
                    bW[j] = f2bf(v);
                }
                accW[nf] = __builtin_amdgcn_mfma_f32_16x16x32_bf16(aW, bW, accW[nf], 0, 0, 0);
            }
        }
        // write Wf^T: C-frag val = Wf[w*16 + crow + r][nf*16 + arow]
#pragma unroll
        for (int nf = 0; nf < 2; ++nf) {
            const int n = nf*16 + arow;
            const int m = w*16 + crow;
            short4v o;
            o[0] = f2bf(accW[nf][0]);
            o[1] = f2bf(accW[nf][1]);
            o[2] = f2bf(accW[nf][2]);
            o[3] = f2bf(accW[nf][3]);
            *(short4v*)&sWfT[n][m] = o;
        }
    }
    __syncthreads();   // B1: publish sA (x) + sWfT

    // ---- phase 3: GEMM1 h1(96x128) = x @ W1, cols [ncol0, ncol0+16);
    //      pure ds_read + MFMA (B-frags already in regs); h1 -> sH
    {
        f32x4 acc[6];
#pragma unroll
        for (int mf = 0; mf < 6; ++mf) acc[mf] = (f32x4){0,0,0,0};

#pragma unroll
        for (int kb = 0; kb < 4; ++kb) {
            const int kof = kb*32 + kgrp;
#pragma unroll
            for (int mf = 0; mf < 6; ++mf) {
                const short8 af = *(const short8*)&sA[mf*16 + arow][kof];
                acc[mf] = __builtin_amdgcn_mfma_f32_16x16x32_bf16(af, pb[kb], acc[mf], 0, 0, 0);
            }
        }

        // h1 = relu(acc + b1) -> sH as bf16
        // C/D layout: col = lane&15, row = (lane>>4)*4 + reg   [m89-verified]
        const int col  = ncol0 + arow;
        const float bias = sb1[col];
#pragma unroll
        for (int mf = 0; mf < 6; ++mf) {
#pragma unroll
            for (int r = 0; r < 4; ++r) {
                float h = acc[mf][r] + bias;
                h = h > 0.f ? h : 0.f;
                sH[mf*16 + crow + r][col] = f2bf(h);
            }
        }
    }
    __syncthreads();   // B2: publish h1

    // ---- attention weights = 1.0 (independent; off the staging-critical path)
    for (int i = t; i < 528; i += NT) {       // 256 blocks x 528 = 135168 float4
        const float4 one4 = {1.f, 1.f, 1.f, 1.f};
        ((float4*)aout)[(size_t)blk*528 + i] = one4;
    }

    // ---- phase 4: GEMM2  m(96x24) = h1 @ Wf; 12 (mf,nf) pairs, 2 on waves 0-5
    if (w < 6) {
        f32x4 acc2[2];
        acc2[0] = (f32x4){0,0,0,0};
        acc2[1] = (f32x4){0,0,0,0};
#pragma unroll
        for (int pp = 0; pp < 2; ++pp) {
            const int p = w*2 + pp, mf = p >> 1, nf = p & 1;
#pragma unroll
            for (int kb = 0; kb < 4; ++kb) {
                const int kof = kb*32 + kgrp;
                const short8 af = *(const short8*)&sH[mf*16 + arow][kof];
                const short8 bf = *(const short8*)&sWfT[nf*16 + arow][kof];
                acc2[pp] = __builtin_amdgcn_mfma_f32_16x16x32_bf16(af, bf, acc2[pp], 0, 0, 0);
            }
        }
        // write m -> smv (zero rows whose in-batch index is out of range)
#pragma unroll
        for (int pp = 0; pp < 2; ++pp) {
            const int p = w*2 + pp, mf = p >> 1, nf = p & 1;
            const int col = nf*16 + arow;
            if (col < HIDv) {
#pragma unroll
                for (int r = 0; r < 4; ++r) {
                    const int row = mf*16 + crow + r;
                    const int l = l0 - Av + row;
                    smv[row][col] = (l >= 0 && l < Lv) ? acc2[pp][r] : 0.f;
                }
            }
        }
    }
    __syncthreads();   // B3: publish m

    // ---- phase 5: 33-tap window sum + fc2_b + relu -> sh2 (direct taps,
    //      independent reads -> single waitcnt; 1536 elems / 512 thr = 3 each)
    for (int i = t; i < TILE*HIDv; i += NT) {
        const int r = i / HIDv, c = i % HIDv;
        float s = 0.f;
#pragma unroll
        for (int ww = 0; ww < Wwin; ++ww) s += smv[r + ww][c];
        const float h = s + fc2b[c];
        sh2[r][c] = h > 0.f ? h : 0.f;
    }
    __syncthreads();   // B4: publish h2

    // ---- phase 6: fc3 (64x24)@(24x2) + b -> out
    if (t < TILE*OUTv) {
        const int r = t >> 1, oc = t & 1;
        float a = fc3b[oc];
#pragma unroll
        for (int c = 0; c < HIDv; ++c)
            a = fmaf(sh2[r][c], fc3w[c*OUTv + oc], a);
        out[(size_t)(g0 + r)*OUTv + oc] = a;
    }
}

// ---------------------------------------------------------------------------
extern "C" void kernel_launch(void* const* d_in, const int* in_sizes, int n_in,
                              void* d_out, int out_size, void* d_ws, size_t ws_size,
                              hipStream_t stream) {
    const float* x     = (const float*)d_in[0];
    const float* fc1_w = (const float*)d_in[1];
    const float* fc1_b = (const float*)d_in[2];
    // d_in[3] = Wq_w, d_in[4] = Wk_w : dead (softmax over singleton axis)
    const float* Wv_w  = (const float*)d_in[5];
    const float* fc2_w = (const float*)d_in[6];
    const float* fc2_b = (const float*)d_in[7];
    const float* fc3_w = (const float*)d_in[8];
    const float* fc3_b = (const float*)d_in[9];

    float* out  = (float*)d_out;                    // (B,L,2)    32768 floats
    float* aout = (float*)d_out + NROWS * OUTv;     // (B,L,1,33) 540672 floats

    k_all<<<dim3(NBLK), dim3(NT), 0, stream>>>(x, fc1_w, fc1_b, Wv_w, fc2_w,
                                               fc2_b, fc3_w, fc3_b, out, aout);
}

// Round 11
// 14.686 us; speedup vs baseline: 1.1531x; 1.1531x over previous
//
#include <hip/hip_runtime.h>

// Problem constants
constexpr int Bv   = 4;
constexpr int Lv   = 4096;
constexpr int Dv   = 128;
constexpr int Av   = 16;
constexpr int Wwin = 2*Av + 1;  // 33
constexpr int OUTv = 2;
constexpr int HIDv = 24;
constexpr int NROWS = Bv * Lv;  // 16384

constexpr int TILE  = 64;           // output rows per block
constexpr int SROWS = TILE + 2*Av;  // 96 staged rows
constexpr int NBLK  = NROWS / TILE; // 256
constexpr int NT    = 512;          // threads per block (8 waves)

typedef __attribute__((ext_vector_type(8))) short short8;   // 8 bf16 (4 VGPR)
typedef __attribute__((ext_vector_type(4))) short short4v;  // 4 bf16 (8B)
typedef __attribute__((ext_vector_type(4))) float f32x4;    // MFMA acc

__device__ __forceinline__ short f2bf(float f) {  // RNE fp32->bf16 (3 VALU)
    unsigned u = __builtin_bit_cast(unsigned, f);
    u += 0x7FFFu + ((u >> 16) & 1u);
    return (short)(u >> 16);
}

// ---------------------------------------------------------------------------
// Single fused kernel, TILE=64 rows/block (+16 halo each side), 8 waves.
//   Wf = Wv@fc2 per-block via MFMA (1 row-frag/wave)
//   h1 = relu(x@W1+b1) via MFMA (16 cols/wave, inline W1 B-frag loads —
//        register prefetch twice measured as neutral/regressing, R7/R10)
//   m  = h1@Wf via MFMA (2 frag-pairs/wave, waves 0-5)
//   33-tap window sum + fc2_b + relu; fc3 -> out; a-output = 1.0
// grid 256, 512 threads, LDS ~77.4 KB -> 1 block/CU (2 waves/SIMD)
__global__ __launch_bounds__(NT) void k_all(const float* __restrict__ x,
                                            const float* __restrict__ W1,
                                            const float* __restrict__ b1,
                                            const float* __restrict__ Wv,
                                            const float* __restrict__ fc2,
                                            const float* __restrict__ fc2b,
                                            const float* __restrict__ fc3w,
                                            const float* __restrict__ fc3b,
                                            float* __restrict__ out,
                                            float* __restrict__ aout) {
    __shared__ short sA[SROWS][136];    // x tile, bf16   (26112 B)
    __shared__ short sH[SROWS][136];    // h1, bf16       (26112 B)
    __shared__ short sWfT[32][136];     // Wf^T bf16      (8704 B)
    __shared__ float smv[SROWS][25];    // m, f32         (9600 B)
    __shared__ float sh2[TILE][25];     // h2, f32        (6400 B)
    __shared__ float sb1[Dv];           // 512 B

    const int t = threadIdx.x, blk = blockIdx.x;
    const int g0 = blk * TILE;               // global output row base
    const int bb = g0 >> 12;                 // batch index
    const int l0 = g0 & (Lv - 1);            // in-batch row base
    const int lane = t & 63, w = t >> 6;     // 8 waves
    const int arow = lane & 15;
    const int kgrp = (lane >> 4) * 8;
    const int crow = (lane >> 4) * 4;
    const int ncol0 = w * 16;                // GEMM1: 16 cols per wave

    // ---- phase 1: stage x tile (rows l0-16 .. l0+79), bf16, zero outside [0,Lv)
    for (int i = t; i < SROWS*32; i += NT) {           // 6 iters
        const int r = i >> 5, c4 = i & 31;
        const int l = l0 - Av + r;
        short4v o = {0, 0, 0, 0};
        if (l >= 0 && l < Lv) {
            const float4 v = *(const float4*)&x[((size_t)bb*Lv + l)*Dv + c4*4];
            o[0] = f2bf(v.x); o[1] = f2bf(v.y); o[2] = f2bf(v.z); o[3] = f2bf(v.w);
        }
        *(short4v*)&sA[r][c4*4] = o;
    }
    if (t < Dv) sb1[t] = b1[t];

    // ---- phase 2: Wf = Wv @ fc2 via MFMA; wave w owns Wf rows [w*16, w*16+16)
    {
        f32x4 accW[2];
        accW[0] = (f32x4){0,0,0,0};
        accW[1] = (f32x4){0,0,0,0};
#pragma unroll
        for (int kb = 0; kb < 4; ++kb) {
            const int kof = kb*32 + kgrp;
            const int m = w*16 + arow;
            const float4 v0 = *(const float4*)&Wv[(size_t)m*Dv + kof];
            const float4 v1 = *(const float4*)&Wv[(size_t)m*Dv + kof + 4];
            short8 aW;
            aW[0] = f2bf(v0.x); aW[1] = f2bf(v0.y); aW[2] = f2bf(v0.z); aW[3] = f2bf(v0.w);
            aW[4] = f2bf(v1.x); aW[5] = f2bf(v1.y); aW[6] = f2bf(v1.z); aW[7] = f2bf(v1.w);
#pragma unroll
            for (int nf = 0; nf < 2; ++nf) {
                const int n = nf*16 + arow;
                short8 bW;
#pragma unroll
                for (int j = 0; j < 8; ++j) {
                    const float v = (n < HIDv) ? fc2[(size_t)(kof + j)*HIDv + n] : 0.f;
                    bW[j] = f2bf(v);
                }
                accW[nf] = __builtin_amdgcn_mfma_f32_16x16x32_bf16(aW, bW, accW[nf], 0, 0, 0);
            }
        }
        // write Wf^T: C-frag val = Wf[w*16 + crow + r][nf*16 + arow]
#pragma unroll
        for (int nf = 0; nf < 2; ++nf) {
            const int n = nf*16 + arow;
            const int m = w*16 + crow;
            short4v o;
            o[0] = f2bf(accW[nf][0]);
            o[1] = f2bf(accW[nf][1]);
            o[2] = f2bf(accW[nf][2]);
            o[3] = f2bf(accW[nf][3]);
            *(short4v*)&sWfT[n][m] = o;
        }
    }
    __syncthreads();   // B1: publish sA (x) + sWfT

    // ---- phase 3: GEMM1 h1(96x128) = x @ W1, cols [ncol0, ncol0+16);
    //      inline W1 B-frag loads (L2-resident), A from LDS; h1 -> sH
    {
        f32x4 acc[6];
#pragma unroll
        for (int mf = 0; mf < 6; ++mf) acc[mf] = (f32x4){0,0,0,0};

        const int n0 = ncol0 + arow;
#pragma unroll
        for (int kb = 0; kb < 4; ++kb) {
            const int kof = kb*32 + kgrp;
            float a0[8];
#pragma unroll
            for (int j = 0; j < 8; ++j)
                a0[j] = W1[(size_t)(kof + j)*Dv + n0];
            short8 bf;
#pragma unroll
            for (int j = 0; j < 8; ++j) bf[j] = f2bf(a0[j]);
#pragma unroll
            for (int mf = 0; mf < 6; ++mf) {
                const short8 af = *(const short8*)&sA[mf*16 + arow][kof];
                acc[mf] = __builtin_amdgcn_mfma_f32_16x16x32_bf16(af, bf, acc[mf], 0, 0, 0);
            }
        }

        // h1 = relu(acc + b1) -> sH as bf16
        // C/D layout: col = lane&15, row = (lane>>4)*4 + reg   [m89-verified]
        const int col  = ncol0 + arow;
        const float bias = sb1[col];
#pragma unroll
        for (int mf = 0; mf < 6; ++mf) {
#pragma unroll
            for (int r = 0; r < 4; ++r) {
                float h = acc[mf][r] + bias;
                h = h > 0.f ? h : 0.f;
                sH[mf*16 + crow + r][col] = f2bf(h);
            }
        }
    }
    __syncthreads();   // B2: publish h1

    // ---- attention weights = 1.0 (independent; overlaps GEMM2, off the
    //      staging-critical pre-B1 path)
    for (int i = t; i < 528; i += NT) {       // 256 blocks x 528 = 135168 float4
        const float4 one4 = {1.f, 1.f, 1.f, 1.f};
        ((float4*)aout)[(size_t)blk*528 + i] = one4;
    }

    // ---- phase 4: GEMM2  m(96x24) = h1 @ Wf; 12 (mf,nf) pairs, 2 on waves 0-5
    if (w < 6) {
        f32x4 acc2[2];
        acc2[0] = (f32x4){0,0,0,0};
        acc2[1] = (f32x4){0,0,0,0};
#pragma unroll
        for (int pp = 0; pp < 2; ++pp) {
            const int p = w*2 + pp, mf = p >> 1, nf = p & 1;
#pragma unroll
            for (int kb = 0; kb < 4; ++kb) {
                const int kof = kb*32 + kgrp;
                const short8 af = *(const short8*)&sH[mf*16 + arow][kof];
                const short8 bf = *(const short8*)&sWfT[nf*16 + arow][kof];
                acc2[pp] = __builtin_amdgcn_mfma_f32_16x16x32_bf16(af, bf, acc2[pp], 0, 0, 0);
            }
        }
        // write m -> smv (zero rows whose in-batch index is out of range)
#pragma unroll
        for (int pp = 0; pp < 2; ++pp) {
            const int p = w*2 + pp, mf = p >> 1, nf = p & 1;
            const int col = nf*16 + arow;
            if (col < HIDv) {
#pragma unroll
                for (int r = 0; r < 4; ++r) {
                    const int row = mf*16 + crow + r;
                    const int l = l0 - Av + row;
                    smv[row][col] = (l >= 0 && l < Lv) ? acc2[pp][r] : 0.f;
                }
            }
        }
    }
    __syncthreads();   // B3: publish m

    // ---- phase 5: 33-tap window sum + fc2_b + relu -> sh2 (direct taps,
    //      independent reads -> single waitcnt; 1536 elems / 512 thr = 3 each)
    for (int i = t; i < TILE*HIDv; i += NT) {
        const int r = i / HIDv, c = i % HIDv;
        float s = 0.f;
#pragma unroll
        for (int ww = 0; ww < Wwin; ++ww) s += smv[r + ww][c];
        const float h = s + fc2b[c];
        sh2[r][c] = h > 0.f ? h : 0.f;
    }
    __syncthreads();   // B4: publish h2

    // ---- phase 6: fc3 (64x24)@(24x2) + b -> out
    if (t < TILE*OUTv) {
        const int r = t >> 1, oc = t & 1;
        float a = fc3b[oc];
#pragma unroll
        for (int c = 0; c < HIDv; ++c)
            a = fmaf(sh2[r][c], fc3w[c*OUTv + oc], a);
        out[(size_t)(g0 + r)*OUTv + oc] = a;
    }
}

// ---------------------------------------------------------------------------
extern "C" void kernel_launch(void* const* d_in, const int* in_sizes, int n_in,
                              void* d_out, int out_size, void* d_ws, size_t ws_size,
                              hipStream_t stream) {
    const float* x     = (const float*)d_in[0];
    const float* fc1_w = (const float*)d_in[1];
    const float* fc1_b = (const float*)d_in[2];
    // d_in[3] = Wq_w, d_in[4] = Wk_w : dead (softmax over singleton axis)
    const float* Wv_w  = (const float*)d_in[5];
    const float* fc2_w = (const float*)d_in[6];
    const float* fc2_b = (const float*)d_in[7];
    const float* fc3_w = (const float*)d_in[8];
    const float* fc3_b = (const float*)d_in[9];

    float* out  = (float*)d_out;                    // (B,L,2)    32768 floats
    float* aout = (float*)d_out + NROWS * OUTv;     // (B,L,1,33) 540672 floats

    k_all<<<dim3(NBLK), dim3(NT), 0, stream>>>(x, fc1_w, fc1_b, Wv_w, fc2_w,
                                               fc2_b, fc3_w, fc3_b, out, aout);
}